// Round 9
// baseline (10.269 us; speedup 1.0000x reference)
//
#include <hip/hip_runtime.h>
#include <hip/hip_bf16.h>

// Degree-2 Taylor causal linear attention == causal quadratic attention:
//   Y_S[h,s,:] = (1/64) * sum_{s'<=s} (Q[s]·K[s'])^2 * V[s']
//   Y_Z[h,s]   = (1/64) * sum_{s'<=s} (Q[s]·K[s'])^2
// H=8, S=512, DK=32, DV=64, fp32 in/out.
//
// v9 = v8 + three changes:
//  (1) d-interleaved PV tiling: MFMA tile t column n <-> physical d = 4n+t.
//      Lane (g,r15) then needs V[row][4*r15..4*r15+3] contiguous -> V loads
//      become 16 coalesced dwordx4 instead of 64 scalar gathers (same bytes).
//      Only the Y_S store index changes (d = 4*r15 + t).
//  (2) __launch_bounds__(512,2): cap VGPR at 256, no spills, 2 waves/SIMD.
//  (3) nc-bounded cross-wave reduce; inactive waves skip publishes.

typedef __attribute__((ext_vector_type(8))) short short8;   // 8 bf16
typedef __attribute__((ext_vector_type(4))) float floatx4;  // MFMA C/D

constexpr int H_ = 8, S_ = 512, DK = 32, DV = 64;
constexpr float ALPHA = 1.0f / 64.0f;

__device__ __forceinline__ unsigned int pk_bf16(float a, float b) {
    __hip_bfloat162 h = __float22bfloat162_rn(make_float2(a, b));
    union { __hip_bfloat162 h2; unsigned int u; } cvt; cvt.h2 = h;
    return cvt.u;
}
// 8 f32 -> short8 bf16, no unpack VALU (bit-cast of packed words)
__device__ __forceinline__ short8 pack8(float4 a, float4 b) {
    union { unsigned int u[4]; short8 s; } r;
    r.u[0] = pk_bf16(a.x, a.y); r.u[1] = pk_bf16(a.z, a.w);
    r.u[2] = pk_bf16(b.x, b.y); r.u[3] = pk_bf16(b.z, b.w);
    return r.s;
}

__global__ __launch_bounds__(512, 2) void taylor_v9(
    const float* __restrict__ Qg, const float* __restrict__ Kg,
    const float* __restrict__ Vg, float* __restrict__ out)
{
    const int t = threadIdx.x;
    const int c = t >> 6;                  // wave id == 64-key chunk id 0..7
    const int l = t & 63;
    const int h = blockIdx.x & 7;          // head (spreads XCDs)
    const int qt = 31 - (blockIdx.x >> 3); // 16-query tile, deep first
    const int qbase = qt * 16;
    const int nc = (qt >> 2) + 1;          // causal chunk count 1..8
    const int g = l >> 4, r15 = l & 15;

    __shared__ alignas(16) char Ssm[8 * 2048];    // per-wave S^T[16q][64k] bf16, swizzled
    __shared__ alignas(16) float4 Racc[8][4][64]; // [chunk][frag][lane]
    __shared__ float Zb[8][16];                   // per-wave Y_Z partials

    floatx4 acc[4] = {};                   // [tile t]; tile t col n = phys d 4n+t
    float zacc = 0.f;

    if (c < nc) {
        const bool lastc = (c == nc - 1);
        const int kb = c * 64;

        // ---- issue all raw loads up-front (Q, K, then V) ----
        float4 qraw[2];
        {
            const float* qp = Qg + (size_t)(h * S_ + qbase + r15) * DK + g * 8;
            qraw[0] = *(const float4*)qp;
            qraw[1] = *(const float4*)(qp + 4);
        }
        float4 kraw[4][2];
        #pragma unroll
        for (int ktile = 0; ktile < 4; ++ktile) {
            const float* kp = Kg + (size_t)(h * S_ + kb + ktile * 16 + r15) * DK + g * 8;
            kraw[ktile][0] = *(const float4*)kp;
            kraw[ktile][1] = *(const float4*)(kp + 4);
        }
        // V: 16 coalesced dwordx4; lane (g,r15) collects its fragment rows:
        //   vraw4[kc][j] = V[kb + kc*32 + g*8 + j][4*r15 .. 4*r15+3]
        float4 vraw4[2][8];
        {
            const float* vb0 = Vg + (size_t)(h * S_ + kb + g * 8) * DV + 4 * r15;
            #pragma unroll
            for (int kc = 0; kc < 2; ++kc)
                #pragma unroll
                for (int j = 0; j < 8; ++j)
                    vraw4[kc][j] = *(const float4*)(vb0 + (size_t)(kc * 32 + j) * DV);
        }

        // ---- convert Q ----
        short8 qB = pack8(qraw[0], qraw[1]);

        char* ssmW = Ssm + c * 2048;

        // ---- QK^T: S^T[k][q], 4 ktiles, 1 MFMA each ----
        #pragma unroll
        for (int ktile = 0; ktile < 4; ++ktile) {
            short8 kA = pack8(kraw[ktile][0], kraw[ktile][1]);
            floatx4 cc_ = {0.f, 0.f, 0.f, 0.f};
            cc_ = __builtin_amdgcn_mfma_f32_16x16x32_bf16(kA, qB, cc_, 0, 0, 0);
            // C layout: q = col = r15, k = row = g*4 + rr (+16*ktile)
            const int qg = qbase + r15;
            const int k0 = kb + ktile * 16 + g * 4;
            float s[4];
            #pragma unroll
            for (int rr = 0; rr < 4; ++rr) {
                float sv = cc_[rr] * cc_[rr] * ALPHA;
                if (lastc && (k0 + rr > qg)) sv = 0.f;
                s[rr] = sv;
            }
            zacc += (s[0] + s[1]) + (s[2] + s[3]);
            unsigned int p0 = pk_bf16(s[0], s[1]);
            unsigned int p1 = pk_bf16(s[2], s[3]);
            const int kl = ktile * 16 + g * 4;       // key local 0..63
            const int byte = r15 * 128 + (((kl >> 3) ^ (r15 & 7)) << 4) + ((kl & 7) * 2);
            *(uint2*)(ssmW + byte) = make_uint2(p0, p1);
        }

        // ---- convert V: vB[kc][t] elem j = bf16(V[..+j][4*r15+t]) ----
        short8 vB[2][4];
        #pragma unroll
        for (int kc = 0; kc < 2; ++kc) {
            union { unsigned int u[4]; short8 s; } r0, r1, r2, r3;
            #pragma unroll
            for (int w = 0; w < 4; ++w) {
                float4 e = vraw4[kc][2 * w];
                float4 o = vraw4[kc][2 * w + 1];
                r0.u[w] = pk_bf16(e.x, o.x);
                r1.u[w] = pk_bf16(e.y, o.y);
                r2.u[w] = pk_bf16(e.z, o.z);
                r3.u[w] = pk_bf16(e.w, o.w);
            }
            vB[kc][0] = r0.s; vB[kc][1] = r1.s; vB[kc][2] = r2.s; vB[kc][3] = r3.s;
        }

        // ---- PV: Y[q][4n+t] += S[q][64k] * V[64k][4n+t] ----
        #pragma unroll
        for (int kc = 0; kc < 2; ++kc) {
            const int gi = kc * 4 + g;               // 8-key granule for A-frag
            short8 sA = *(const short8*)(ssmW + r15 * 128 + ((gi ^ (r15 & 7)) << 4));
            #pragma unroll
            for (int tt = 0; tt < 4; ++tt)
                acc[tt] = __builtin_amdgcn_mfma_f32_16x16x32_bf16(
                    sA, vB[kc][tt], acc[tt], 0, 0, 0);
        }

        // zacc: sum over the 4 lane-groups
        zacc += __shfl_xor(zacc, 16);
        zacc += __shfl_xor(zacc, 32);

        // ---- publish partials (active waves only) ----
        #pragma unroll
        for (int f = 0; f < 4; ++f) {
            floatx4 a = acc[f];
            Racc[c][f][l] = make_float4(a[0], a[1], a[2], a[3]);
        }
        if (l < 16) Zb[c][l] = zacc;
    }
    __syncthreads();

    // ---- cross-wave reduce over the nc active chunks; waves 0..3 own tile f=c ----
    if (c < 4) {
        float4 sum = make_float4(0.f, 0.f, 0.f, 0.f);
        for (int cw = 0; cw < nc; ++cw) {
            float4 v = Racc[cw][c][l];
            sum.x += v.x; sum.y += v.y; sum.z += v.z; sum.w += v.w;
        }
        const int d = 4 * r15 + c;                    // interleaved tiling
        float sv[4] = {sum.x, sum.y, sum.z, sum.w};
        #pragma unroll
        for (int rr = 0; rr < 4; ++rr) {
            int q = qbase + g * 4 + rr;
            out[(size_t)(h * S_ + q) * DV + d] = sv[rr];
        }
    }
    // ---- Y_Z ----
    if (t < 16) {
        float z = 0.f;
        for (int cw = 0; cw < nc; ++cw) z += Zb[cw][t];
        out[(size_t)(H_ * S_ * DV) + h * S_ + qbase + t] = z;
    }
}

extern "C" void kernel_launch(void* const* d_in, const int* in_sizes, int n_in,
                              void* d_out, int out_size, void* d_ws, size_t ws_size,
                              hipStream_t stream) {
    const float* Q = (const float*)d_in[0];
    const float* K = (const float*)d_in[1];
    const float* V = (const float*)d_in[2];
    // d_in[3]=M, d_in[4]=C folded into the (q.k)^2 identity; d_in[5]=continue_prev==0.
    float* out = (float*)d_out;

    taylor_v9<<<256, 512, 0, stream>>>(Q, K, V, out);   // single dispatch, 1 block/CU
}